// Round 4
// baseline (1111.676 us; speedup 1.0000x reference)
//
#include <hip/hip_runtime.h>
#include <hip/hip_bf16.h>

// ---------------------------------------------------------------------------
// PLTBlock: out = (x Wq^T)( (x Wk^T)^T (x Wv^T) ) Wp^T + bp + x   (linear attn)
// B=8, S=4096, D=1024.  bf16 MFMA 16x16x32, fp32 accum.
// R4: flatmm-style restructure. B fragments load global->VGPR directly
//     (B panels are L2-resident: W=2MiB, kvT=2MiB/batch), LDS holds only A
//     and is double-buffered => ONE barrier/iter whose vmcnt drain waits on
//     loads issued a full iteration earlier (latency hidden under MFMA).
// ---------------------------------------------------------------------------

#define B_DIM 8
#define S_DIM 4096
#define D_DIM 1024
#define M_TOT (B_DIM * S_DIM)   // 32768

using short8 = __attribute__((ext_vector_type(8))) short;
using f32x4  = __attribute__((ext_vector_type(4))) float;

#define TILE_M 128
#define TILE_N 128
#define TILE_K 64

__device__ __forceinline__ void g2l16(const void* g, void* l) {
  __builtin_amdgcn_global_load_lds(
      (const __attribute__((address_space(1))) unsigned int*)g,
      (__attribute__((address_space(3))) unsigned int*)l, 16, 0, 0);
}

__device__ __forceinline__ unsigned short f2b(float f) {
  __hip_bfloat16 h = __float2bfloat16(f);
  return __builtin_bit_cast(unsigned short, h);
}

// C[m,n] = sum_k A[m,k] * Bt[n,k]   (A: MxK row-major, Bt: NxK row-major)
// FINAL=false: C bf16.  FINAL=true: C fp32, += bias[n] + resid[m*ldc+n].
// A LDS rotation: slot c of row r holds global 16B-chunk (c+r)&7.
template<bool FINAL>
__global__ __launch_bounds__(256, 3)
void gemm_bt(const unsigned short* __restrict__ A,
             const unsigned short* __restrict__ Bt,
             void* __restrict__ C,
             int K, int lda, int ldb, int ldc,
             long long sA, long long sB, long long sC,
             const float* __restrict__ bias,
             const float* __restrict__ resid)
{
  // A double-buffer: 2 x 128x64 bf16 = 32 KiB. Epilogue Ct reuses it.
  __shared__ __align__(16) unsigned short smem[2 * TILE_M * TILE_K];

  const int tid  = threadIdx.x;
  const int wave = tid >> 6;
  const int lane = tid & 63;
  const int qd   = lane >> 4;
  const int ln   = lane & 15;
  const int wr   = (wave >> 1) * 64;
  const int wc   = (wave & 1) * 64;

  // XCD-stripe swizzle (xcd ~ flat%8 round-robin).
  const int flat = blockIdx.y * gridDim.x + blockIdx.x;
  const int strp = flat & 7;
  const int t8   = flat >> 3;
  const int bx   = t8 % gridDim.x;
  const int by   = strp * (gridDim.y >> 3) + t8 / gridDim.x;

  const long long m0 = (long long)by * TILE_M;
  const long long n0 = (long long)bx * TILE_N;
  const int bz = blockIdx.z;

  const unsigned short* Ab = A  + (long long)bz * sA;
  const unsigned short* Bb = Bt + (long long)bz * sB;

  // A staging: 128x64 bf16 = 16 KiB/buf; 256 thr x 4 g2l16.
  const int srow = tid >> 3;
  const int scg  = ((tid & 7) + (tid >> 3)) & 7;
  const unsigned short* pA = Ab + (m0 + srow) * lda + scg * 8;
  const long long rsA = 32LL * lda;

  // A fragment row bases + rotation seeds.
  int rowA[4], sA0[4];
#pragma unroll
  for (int i = 0; i < 4; ++i) {
    int ra = wr + i * 16 + ln;
    rowA[i] = ra * 64;  sA0[i] = (qd - ra) & 7;
  }

  // B fragment pointers (direct global): row n0+wc+j*16+ln, col qd*8 (+kk*32).
  const unsigned short* pB[4];
#pragma unroll
  for (int j = 0; j < 4; ++j)
    pB[j] = Bb + (n0 + wc + j * 16 + ln) * (long long)ldb + qd * 8;

  f32x4 acc[4][4];
#pragma unroll
  for (int i = 0; i < 4; ++i)
#pragma unroll
    for (int j = 0; j < 4; ++j)
      acc[i][j] = (f32x4){0.f, 0.f, 0.f, 0.f};

  const int niter = K / TILE_K;

  // ---- prologue: stage A(0) into buf0, load B(0) fragments ----
#pragma unroll
  for (int it = 0; it < 4; ++it) g2l16(pA + it * rsA, smem + wave * 512 + it * 2048);
  short8 bc0[4], bc1[4];
#pragma unroll
  for (int j = 0; j < 4; ++j) { bc0[j] = *(const short8*)(pB[j]); bc1[j] = *(const short8*)(pB[j] + 32); pB[j] += 64; }
  pA += TILE_K;
  __syncthreads();

  for (int k = 0; k < niter; ++k) {
    const bool more = (k + 1 < niter);
    const unsigned short* rd = smem + ((k & 1) << 13);          // read buf
    unsigned short* wrB = (unsigned short*)smem + (((k + 1) & 1) << 13); // write buf

    if (more) {
#pragma unroll
      for (int it = 0; it < 4; ++it) g2l16(pA + it * rsA, wrB + wave * 512 + it * 2048);
    }

    short8 bn0[4], bn1[4];
    if (more) {
#pragma unroll
      for (int j = 0; j < 4; ++j) bn0[j] = *(const short8*)(pB[j]);
    }

    // kk = 0
    {
      short8 af[4];
#pragma unroll
      for (int i = 0; i < 4; ++i)
        af[i] = *(const short8*)(rd + rowA[i] + ((sA0[i] & 7) << 3));
#pragma unroll
      for (int i = 0; i < 4; ++i)
#pragma unroll
        for (int j = 0; j < 4; ++j)
          acc[i][j] = __builtin_amdgcn_mfma_f32_16x16x32_bf16(af[i], bc0[j], acc[i][j], 0, 0, 0);
    }

    if (more) {
#pragma unroll
      for (int j = 0; j < 4; ++j) { bn1[j] = *(const short8*)(pB[j] + 32); pB[j] += 64; }
    }

    // kk = 1
    {
      short8 af[4];
#pragma unroll
      for (int i = 0; i < 4; ++i)
        af[i] = *(const short8*)(rd + rowA[i] + (((sA0[i] + 4) & 7) << 3));
#pragma unroll
      for (int i = 0; i < 4; ++i)
#pragma unroll
        for (int j = 0; j < 4; ++j)
          acc[i][j] = __builtin_amdgcn_mfma_f32_16x16x32_bf16(af[i], bc1[j], acc[i][j], 0, 0, 0);
    }

#pragma unroll
    for (int j = 0; j < 4; ++j) { bc0[j] = bn0[j]; bc1[j] = bn1[j]; }
    pA += TILE_K;
    __syncthreads();   // drains vmcnt: A(k+1)+B(k+1), all issued ~1 iter ago
  }

  // ---- Coalesced epilogue: 4 passes of 32 rows via LDS (stride 132 fp32).
  float* Ct = (float*)smem;   // 32*132*4 = 16896 B < 32 KiB
  const int fr = tid >> 3;
  const int fc = (tid & 7) * 4;
  const int hr = tid >> 4;
  const int hc = (tid & 15) * 4;

#pragma unroll
  for (int p = 0; p < 4; ++p) {
    __syncthreads();
    if ((wr >> 6) == (p >> 1)) {
      const int ibase = (p & 1) * 2;
#pragma unroll
      for (int ii = 0; ii < 2; ++ii)
#pragma unroll
        for (int j = 0; j < 4; ++j)
#pragma unroll
          for (int r = 0; r < 4; ++r)
            Ct[(ii * 16 + qd * 4 + r) * 132 + wc + j * 16 + ln] = acc[ibase + ii][j][r];
    }
    __syncthreads();

    if constexpr (FINAL) {
      float* Cf = (float*)C + (long long)bz * sC;
      const long long grow = m0 + p * 32 + fr;
#pragma unroll
      for (int s = 0; s < 4; ++s) {
        const int c = fc + s * 32;
        float4 v = *(const float4*)(Ct + fr * 132 + c);
        const float4 bb = *(const float4*)(bias + n0 + c);
        const float4 rr = *(const float4*)(resid + grow * ldc + n0 + c);
        v.x += bb.x + rr.x; v.y += bb.y + rr.y;
        v.z += bb.z + rr.z; v.w += bb.w + rr.w;
        *(float4*)(Cf + grow * ldc + n0 + c) = v;
      }
    } else {
      unsigned short* Cb = (unsigned short*)C + (long long)bz * sC;
#pragma unroll
      for (int rs = 0; rs < 2; ++rs) {
        const int row = hr + rs * 16;
        const long long grow = m0 + p * 32 + row;
#pragma unroll
        for (int s = 0; s < 2; ++s) {
          const int c = hc + s * 64;
          float4 v = *(const float4*)(Ct + row * 132 + c);
          ushort4 u;
          u.x = f2b(v.x); u.y = f2b(v.y); u.z = f2b(v.z); u.w = f2b(v.w);
          *(ushort4*)(Cb + grow * ldc + n0 + c) = u;
        }
      }
    }
  }
}

// dst[b][e][s] = src[b*S + s][e]   (src: [B*S, D] bf16, dst: [B, D, S] bf16)
__global__ __launch_bounds__(256)
void transpose_bds(const unsigned short* __restrict__ src,
                   unsigned short* __restrict__ dst)
{
  __shared__ unsigned short tile[64][68];
  const int b  = blockIdx.z;
  const int s0 = blockIdx.x * 64;
  const int e0 = blockIdx.y * 64;
  const int tx = threadIdx.x & 15;
  const int ty = threadIdx.x >> 4;

#pragma unroll
  for (int r = 0; r < 4; ++r) {
    int s = ty * 4 + r;
    ushort4 d = *(const ushort4*)(src + ((size_t)b * S_DIM + s0 + s) * D_DIM + e0 + tx * 4);
    *(ushort4*)&tile[s][tx * 4] = d;
  }
  __syncthreads();
#pragma unroll
  for (int r = 0; r < 4; ++r) {
    int e = ty * 4 + r;
    ushort4 d;
    d.x = tile[tx * 4 + 0][e];
    d.y = tile[tx * 4 + 1][e];
    d.z = tile[tx * 4 + 2][e];
    d.w = tile[tx * 4 + 3][e];
    *(ushort4*)(dst + ((size_t)b * D_DIM + e0 + e) * S_DIM + s0 + tx * 4) = d;
  }
}

__global__ __launch_bounds__(256)
void cast_f32_bf16(const float* __restrict__ src, unsigned short* __restrict__ dst, int n4)
{
  int i = blockIdx.x * 256 + threadIdx.x;
  if (i >= n4) return;
  float4 f = ((const float4*)src)[i];
  ushort4 u;
  u.x = f2b(f.x); u.y = f2b(f.y); u.z = f2b(f.z); u.w = f2b(f.w);
  ((ushort4*)dst)[i] = u;
}

extern "C" void kernel_launch(void* const* d_in, const int* in_sizes, int n_in,
                              void* d_out, int out_size, void* d_ws, size_t ws_size,
                              hipStream_t stream) {
  const float* x  = (const float*)d_in[0];
  const float* Wq = (const float*)d_in[1];
  const float* Wk = (const float*)d_in[2];
  const float* Wv = (const float*)d_in[3];
  const float* Wp = (const float*)d_in[4];
  const float* bp = (const float*)d_in[5];
  float* out = (float*)d_out;
  char* ws = (char*)d_ws;

  unsigned short* xb  = (unsigned short*)(ws + 0);
  unsigned short* Wqb = (unsigned short*)(ws + 67108864);
  unsigned short* Wkb = (unsigned short*)(ws + 69206016);
  unsigned short* Wvb = (unsigned short*)(ws + 71303168);
  unsigned short* Wpb = (unsigned short*)(ws + 73400320);
  unsigned short* qb  = (unsigned short*)(ws + 75497472);
  unsigned short* kb  = (unsigned short*)(ws + 142606336);
  unsigned short* vb  = (unsigned short*)(ws + 209715200);
  unsigned short* kT  = (unsigned short*)(ws + 0);          // reuse xb
  unsigned short* vT  = (unsigned short*)(ws + 142606336);  // reuse kb
  unsigned short* kvT = (unsigned short*)(ws + 209715200);  // reuse vb
  unsigned short* zb  = (unsigned short*)(ws + 0);          // reuse kT

  // ---- casts to bf16 ----
  cast_f32_bf16<<<dim3(M_TOT * D_DIM / 4 / 256), 256, 0, stream>>>(x, xb, M_TOT * D_DIM / 4);
  cast_f32_bf16<<<dim3(D_DIM * D_DIM / 4 / 256), 256, 0, stream>>>(Wq, Wqb, D_DIM * D_DIM / 4);
  cast_f32_bf16<<<dim3(D_DIM * D_DIM / 4 / 256), 256, 0, stream>>>(Wk, Wkb, D_DIM * D_DIM / 4);
  cast_f32_bf16<<<dim3(D_DIM * D_DIM / 4 / 256), 256, 0, stream>>>(Wv, Wvb, D_DIM * D_DIM / 4);
  cast_f32_bf16<<<dim3(D_DIM * D_DIM / 4 / 256), 256, 0, stream>>>(Wp, Wpb, D_DIM * D_DIM / 4);

  // ---- q,k,v = x @ W^T : M=32768, N=1024, K=1024 ----
  dim3 gqkv(D_DIM / TILE_N, M_TOT / TILE_M, 1);
  gemm_bt<false><<<gqkv, 256, 0, stream>>>(xb, Wqb, qb, D_DIM, D_DIM, D_DIM, D_DIM, 0, 0, 0, nullptr, nullptr);
  gemm_bt<false><<<gqkv, 256, 0, stream>>>(xb, Wkb, kb, D_DIM, D_DIM, D_DIM, D_DIM, 0, 0, 0, nullptr, nullptr);
  gemm_bt<false><<<gqkv, 256, 0, stream>>>(xb, Wvb, vb, D_DIM, D_DIM, D_DIM, D_DIM, 0, 0, 0, nullptr, nullptr);

  // ---- kT[b][e][s], vT[b][f][s] ----
  dim3 gt(S_DIM / 64, D_DIM / 64, B_DIM);
  transpose_bds<<<gt, 256, 0, stream>>>(kb, kT);
  transpose_bds<<<gt, 256, 0, stream>>>(vb, vT);

  // ---- kvT[b][f][e] = sum_s vT[f,s] * kT[e,s] : M=N=1024, K=4096 ----
  dim3 gkv(D_DIM / TILE_N, D_DIM / TILE_M, B_DIM);
  gemm_bt<false><<<gkv, 256, 0, stream>>>(vT, kT, kvT, S_DIM, S_DIM, S_DIM, D_DIM,
                                          (long long)D_DIM * S_DIM, (long long)D_DIM * S_DIM,
                                          (long long)D_DIM * D_DIM, nullptr, nullptr);

  // ---- z[b][s][f] = sum_e q[s,e] * kvT[f,e] : M=4096, N=1024, K=1024 ----
  dim3 gz(D_DIM / TILE_N, S_DIM / TILE_M, B_DIM);
  gemm_bt<false><<<gz, 256, 0, stream>>>(qb, kvT, zb, D_DIM, D_DIM, D_DIM, D_DIM,
                                         (long long)S_DIM * D_DIM, (long long)D_DIM * D_DIM,
                                         (long long)S_DIM * D_DIM, nullptr, nullptr);

  // ---- out = z @ Wp^T + bp + x : M=32768, N=1024, K=1024, fp32 out ----
  gemm_bt<true><<<gqkv, 256, 0, stream>>>(zb, Wpb, out, D_DIM, D_DIM, D_DIM, D_DIM,
                                          0, 0, 0, bp, x);
  (void)in_sizes; (void)n_in; (void)out_size; (void)ws_size;
}